// Round 16
// baseline (67.875 us; speedup 1.0000x reference)
//
#include <hip/hip_runtime.h>

// ToeplitzMemoryProjection (HiPPO LagT, alpha=0.5 bilinear).
//
// Recurrence (exact in the truncated lower-tri Toeplitz algebra, verified
// rounds 1-15): with c = 1+0.25dt, g = (1-0.25dt)/c, beta = dt*u/c,
//   x_l[i] = g_l*(x_l[i-1] + x_{l-1}[i]) - x_{l-1}[i-1] + beta_l*[i==0]
//
// R16 = R9 (best, 65.6us) + two isolated instruction-overhead cuts:
//  (a) paired gathers via ds_read2_b32 (g: offsets 2q/2q+1; hb waves 1-3:
//      col-63 of slot pairs, offsets 63/127 and 191/255 per 4-slot base;
//      bl&127 <= 96 -> no mid-chunk slot wrap). 64 -> 32 gather
//      instructions per wave per chunk, identical data and bank behavior,
//      ZERO added serial work (R13's lesson).
//  (b) plain f32x4 stores (not nontemporal): L2 write-back absorbs bursts
//      and the ~32MB tail can retire dirty-in-L2 past kernel end.
// Everything else byte-identical to R9: column-per-lane wavefront, KCH=32,
// SKEW=96, row-indexed ring RSLOT=128 (slot = row & 127, write bank =
// lane%32, conflict-free), flush rows [bl-64, bl-33] at chunk end as
// 8 ds_read_b128 + 8 dwordx4 (coalesced 256B row segments), LDS-only
// barriers (store queue never drained at a barrier).

namespace {

constexpr int LLEN   = 1024;
constexpr int NCHAN  = 256;
constexpr int KCH    = 32;                 // ticks per chunk
constexpr int SKEW   = 96;                 // wave skew; 96-63=33 > KCH-1
constexpr int RSLOT  = 128;                // row slots per ring (pow2)
constexpr int NCHUNK = 43;                 // covers ticks [0,1376) >= 1375
constexpr int GPAD   = 1152;               // g/b padded length

constexpr int G_OFF = 0;
constexpr int B_OFF = GPAD;
constexpr int R_OFF = 2 * GPAD;
constexpr int LDS_FLOATS = R_OFF + 4 * RSLOT * 64;
constexpr size_t LDS_BYTES = (size_t)LDS_FLOATS * 4;   // 140288 B

using f32x4 = __attribute__((ext_vector_type(4))) float;
using f32x2 = __attribute__((ext_vector_type(2))) float;

__device__ __forceinline__ float dpp_shr1(float v) {
    // lane i <- lane i-1; lane 0 <- 0
    return __int_as_float(__builtin_amdgcn_update_dpp(
        0, __float_as_int(v), 0x138 /*WAVE_SHR1*/, 0xF, 0xF, false));
}
__device__ __forceinline__ unsigned lds_a(const void* p) {
    return (unsigned)(unsigned long long)p;
}
__device__ __forceinline__ void ds_rd2(f32x2& d, unsigned a, int o0, int o1) {
    asm volatile("ds_read2_b32 %0, %1 offset0:%2 offset1:%3"
                 : "=v"(d) : "v"(a), "i"(o0), "i"(o1));
}
__device__ __forceinline__ void compiler_mem_fence() {
    asm volatile("" ::: "memory");
}
__device__ __forceinline__ void wait_lgkm0_fence() {
    asm volatile("s_waitcnt lgkmcnt(0)" ::: "memory");
    __builtin_amdgcn_sched_barrier(0);
}
// LDS-only barrier: orders ring handoffs without draining the store queue.
__device__ __forceinline__ void lds_barrier() {
    __builtin_amdgcn_sched_barrier(0);
    asm volatile("s_waitcnt lgkmcnt(0)" ::: "memory");
    __builtin_amdgcn_s_barrier();
    __builtin_amdgcn_sched_barrier(0);
}

// One 32-tick chunk. hb source: W0 -> b_arr (beta, aligned b128);
// else -> left wave's ring col 63 via paired ds_read2.
template <bool W0, bool MASKED>
__device__ __forceinline__ void do_chunk(
    const int T0, const int bl, const int lane, const bool lane0,
    const float* __restrict__ g_arr, const float* __restrict__ hb_src,
    const unsigned g_base, const unsigned lf_base,
    float* __restrict__ my_ring, float& prev_own, float& prev_left)
{
    float hb[KCH];
    float gpre[KCH];

    if (!MASKED) {
        // ---- paired gathers: 16 read2 (g) + 16 read2 / 8 b128 (hb) ----
        f32x2 g2[16];
        const unsigned ga = g_base + 4u * (unsigned)(bl - lane);
        #pragma unroll
        for (int q = 0; q < 16; ++q) ds_rd2(g2[q], ga, 2 * q, 2 * q + 1);
        if (W0) {
            #pragma unroll
            for (int q = 0; q < KCH / 4; ++q) {
                const f32x4 t =
                    *reinterpret_cast<const f32x4*>(hb_src + T0 + 4 * q);
                hb[4*q+0] = t[0]; hb[4*q+1] = t[1];
                hb[4*q+2] = t[2]; hb[4*q+3] = t[3];
            }
        } else {
            // col 63 of slots (bl&127)+4q .. +3 (no wrap: bl&127 <= 96)
            f32x2 h2[16];
            const unsigned hbase = lf_base + ((unsigned)(bl & (RSLOT - 1)) << 8);
            #pragma unroll
            for (int q = 0; q < 8; ++q) {
                const unsigned a = hbase + (unsigned)(q << 10);
                ds_rd2(h2[2*q+0], a, 63, 127);
                ds_rd2(h2[2*q+1], a, 191, 255);
            }
            #pragma unroll
            for (int s = 0; s < KCH; ++s) hb[s] = h2[s >> 1][s & 1];
        }
        wait_lgkm0_fence();
        #pragma unroll
        for (int s = 0; s < KCH; ++s) gpre[s] = g2[s >> 1][s & 1];
    } else {
        #pragma unroll
        for (int s = 0; s < KCH; ++s) {
            const int li = min(max(bl - lane + s, 0), LLEN - 1);
            gpre[s] = g_arr[li];
            if (W0) hb[s] = hb_src[T0 + s];            // pad covers range
            else    hb[s] = hb_src[(((bl + s) & (RSLOT - 1)) << 6) + 63];
        }
    }

    const int m0 = bl - lane;              // this lane's row at s=0
    #pragma unroll
    for (int s = 0; s < KCH; ++s) {
        const float gg = gpre[s];
        float cl = dpp_shr1(prev_own);
        float ct;
        if (W0) {
            ct = (lane0 ? hb[s] : 0.0f) - prev_left;   // lane0: +beta
        } else {
            cl += lane0 ? hb[s] : 0.0f;                // lane0: handoff
            ct = 0.0f - prev_left;
        }
        const float x = fmaf(gg, cl, fmaf(gg, prev_own, ct));
        my_ring[(((m0 + s) & (RSLOT - 1)) << 6) + lane] = x;
        if (MASKED) {
            const bool act = (unsigned)(m0 + s) < (unsigned)LLEN;
            prev_left = act ? cl : prev_left;
            prev_own  = act ? x  : prev_own;
        } else {
            prev_left = cl;
            prev_own  = x;
        }
    }
}

__global__ __launch_bounds__(256, 1)
void toeplitz_scan(const float* __restrict__ vin,   // inputs (L, 256)
                   const float* __restrict__ dtin,  // dt     (L, 256)
                   float* __restrict__ out)         // (L, 256, 256)
{
    extern __shared__ float lds[];
    float* g_arr = lds + G_OFF;   // [GPAD]
    float* b_arr = lds + B_OFF;   // [GPAD]
    float* ring  = lds + R_OFF;   // [4][RSLOT][64], row-indexed slots

    const int ch  = blockIdx.x;
    const int tid = threadIdx.x;

    // ---- per-channel g[l], beta[l] (+ zero pad) ----
    #pragma unroll
    for (int k = 0; k < LLEN / 256; ++k) {
        const int l = tid + 256 * k;
        const float d = dtin[l * NCHAN + ch];
        const float u = vin[l * NCHAN + ch];
        const float ic = 1.0f / (1.0f + 0.25f * d);
        g_arr[l] = (1.0f - 0.25f * d) * ic;
        b_arr[l] = d * u * ic;
    }
    if (tid < GPAD - LLEN) {
        g_arr[LLEN + tid] = 1.0f;
        b_arr[LLEN + tid] = 0.0f;
    }
    __syncthreads();

    const int wave = tid >> 6, lane = tid & 63;
    const bool w0    = (wave == 0);
    const bool lane0 = (lane == 0);
    const int wskew  = wave * SKEW;

    float* my_ring = ring + wave * (RSLOT * 64);
    const float* lf_ring = ring + (wave > 0 ? (wave - 1) : 0) * (RSLOT * 64);
    const unsigned g_base  = lds_a(g_arr);
    const unsigned lf_base = lds_a(lf_ring);

    float prev_own = 0.0f, prev_left = 0.0f;

    const int rq = lane >> 4;              // flush: row within 4-row group
    const int cq = (lane & 15) << 2;       // flush: col-quad start
    float* const out_col = out + (size_t)(ch * 256 + wave * 64 + cq);

    for (int c = 0; c < NCHUNK; ++c) {
        const int T0 = c * KCH;
        const int bl = T0 - wskew;         // lane0's row at s=0 (mult of 32)

        if (bl >= 0 && bl <= 1056) {       // any lane active this chunk
            const bool fast = (bl >= 64) && (bl <= LLEN - KCH);
            if (w0) {
                if (fast)
                    do_chunk<true, false>(T0, bl, lane, lane0, g_arr, b_arr,
                                          g_base, lf_base, my_ring,
                                          prev_own, prev_left);
                else
                    do_chunk<true, true>(T0, bl, lane, lane0, g_arr, b_arr,
                                         g_base, lf_base, my_ring,
                                         prev_own, prev_left);
            } else {
                if (fast)
                    do_chunk<false, false>(T0, bl, lane, lane0, g_arr, lf_ring,
                                           g_base, lf_base, my_ring,
                                           prev_own, prev_left);
                else
                    do_chunk<false, true>(T0, bl, lane, lane0, g_arr, lf_ring,
                                          g_base, lf_base, my_ring,
                                          prev_own, prev_left);
            }
        }

        // ---- flush rows [F, F+31] (4-row groups; complete at tick T0+30) --
        const int F = T0 - wskew - 64;
        if (F >= 0 && F <= LLEN - KCH) {
            compiler_mem_fence();          // ring writes stay above reads
            const float* rb = my_ring + ((F & (RSLOT - 1)) << 6) + cq;
            float* ob = out_col + (size_t)(F + rq) * (NCHAN * 256);
            #pragma unroll
            for (int q = 0; q < 8; ++q) {
                const f32x4 v =
                    *reinterpret_cast<const f32x4*>(rb + ((4 * q + rq) << 6));
                *reinterpret_cast<f32x4*>(ob) = v;   // plain store: L2 absorbs
                ob += (size_t)4 * (NCHAN * 256);
            }
        }
        lds_barrier();
    }
}

} // namespace

extern "C" void kernel_launch(void* const* d_in, const int* in_sizes, int n_in,
                              void* d_out, int out_size, void* d_ws, size_t ws_size,
                              hipStream_t stream) {
    (void)in_sizes; (void)n_in; (void)d_ws; (void)ws_size; (void)out_size;
    const float* vin  = (const float*)d_in[0];   // "inputs"
    const float* dtin = (const float*)d_in[1];   // "dt"
    float* out = (float*)d_out;

    (void)hipFuncSetAttribute(reinterpret_cast<const void*>(toeplitz_scan),
                              hipFuncAttributeMaxDynamicSharedMemorySize,
                              (int)LDS_BYTES);

    toeplitz_scan<<<NCHAN, 256, LDS_BYTES, stream>>>(vin, dtin, out);
}

// Round 17
// 65.767 us; speedup vs baseline: 1.0321x; 1.0321x over previous
//
#include <hip/hip_runtime.h>

// ToeplitzMemoryProjection (HiPPO LagT, alpha=0.5 bilinear).
//
// Recurrence (exact in the truncated lower-tri Toeplitz algebra, verified
// rounds 1-16): with c = 1+0.25dt, g = (1-0.25dt)/c, beta = dt*u/c,
//   x_l[i] = g_l*(x_l[i-1] + x_{l-1}[i]) - x_{l-1}[i-1] + beta_l*[i==0]
//
// R17 = R9 (best, 65.6us) + ONE parameter change: ring row stride 64 -> 68
// dwords (272 B, 16B-aligned).
//
// WHY: R9's flush ds_read_b128 had dword index slot*64 + 4*(lane&15); with
// stride 64 = 0 mod 32, EVERY row hits the same 8 even banks -> 256 dwords
// into 8 banks = 4-way conflict (~48cy/instr). That conflict was ~40% of
// the LDS pipe: 3760 cy/chunk * 43 chunks = 67us at 2.4GHz -- matching the
// observed 65.6us exactly (model finally closes, no clock-throttle fudge).
// With stride 68 (= 4 mod 32) the bank base rotates 4 per slot:
//  - flush instr (4 slots x 16 quads): banks (4*slot + 4m + 0..3) tile all
//    32 banks exactly 8x -> conflict-free optimum (12cy).
//  - ring write: bank (4*slot + lane) % 32 -> exactly 2 lanes/bank (free).
//  - hb col-63 reads are broadcasts (unaffected); g-reads unchanged (free).
// Everything else byte-identical to R9: column-per-lane wavefront, KCH=32,
// SKEW=96, RSLOT=128 (slot = row & 127), flush rows [bl-64, bl-33] at chunk
// end (8 b128 + 8 nontemporal dwordx4, coalesced 256B segments), LDS-only
// barriers (store queue drains in background), masked edge chunks.

namespace {

constexpr int LLEN   = 1024;
constexpr int NCHAN  = 256;
constexpr int KCH    = 32;                 // ticks per chunk
constexpr int SKEW   = 96;                 // wave skew; 96-63=33 > KCH-1
constexpr int RSLOT  = 128;                // row slots per ring (pow2)
constexpr int RSTR   = 68;                 // ring row stride in dwords (272B)
constexpr int NCHUNK = 43;                 // covers ticks [0,1376) >= 1375
constexpr int GPAD   = 1152;               // g/b padded length

constexpr int G_OFF = 0;
constexpr int B_OFF = GPAD;
constexpr int R_OFF = 2 * GPAD;
constexpr int LDS_FLOATS = R_OFF + 4 * RSLOT * RSTR;
constexpr size_t LDS_BYTES = (size_t)LDS_FLOATS * 4;   // 148480 B

using f32x4 = __attribute__((ext_vector_type(4))) float;

__device__ __forceinline__ float dpp_shr1(float v) {
    // lane i <- lane i-1; lane 0 <- 0
    return __int_as_float(__builtin_amdgcn_update_dpp(
        0, __float_as_int(v), 0x138 /*WAVE_SHR1*/, 0xF, 0xF, false));
}
__device__ __forceinline__ void compiler_mem_fence() {
    asm volatile("" ::: "memory");
}
// LDS-only barrier: orders ring handoffs without draining the store queue.
__device__ __forceinline__ void lds_barrier() {
    __builtin_amdgcn_sched_barrier(0);
    asm volatile("s_waitcnt lgkmcnt(0)" ::: "memory");
    __builtin_amdgcn_s_barrier();
    __builtin_amdgcn_sched_barrier(0);
}

// One 32-tick chunk. hb source: W0 -> b_arr (beta, aligned b128);
// else -> left wave's ring col 63 (broadcast b32 reads).
template <bool W0, bool MASKED>
__device__ __forceinline__ void do_chunk(
    const int T0, const int bl, const int lane, const bool lane0,
    const float* __restrict__ g_arr, const float* __restrict__ hb_src,
    float* __restrict__ my_ring, float& prev_own, float& prev_left)
{
    float hb[KCH];
    if (W0) {
        #pragma unroll
        for (int q = 0; q < KCH / 4; ++q) {
            const f32x4 t =
                *reinterpret_cast<const f32x4*>(hb_src + T0 + 4 * q);
            hb[4*q+0] = t[0]; hb[4*q+1] = t[1];
            hb[4*q+2] = t[2]; hb[4*q+3] = t[3];
        }
    } else {
        #pragma unroll
        for (int s = 0; s < KCH; ++s)
            hb[s] = hb_src[((bl + s) & (RSLOT - 1)) * RSTR + 63];
    }

    const int m0 = bl - lane;              // this lane's row at s=0
    #pragma unroll
    for (int s = 0; s < KCH; ++s) {
        int li = m0 + s;
        if (MASKED) li = min(max(li, 0), LLEN - 1);
        const float gg = g_arr[li];
        float cl = dpp_shr1(prev_own);
        float ct;
        if (W0) {
            ct = (lane0 ? hb[s] : 0.0f) - prev_left;   // lane0: +beta
        } else {
            cl += lane0 ? hb[s] : 0.0f;                // lane0: handoff
            ct = 0.0f - prev_left;
        }
        const float x = fmaf(gg, cl, fmaf(gg, prev_own, ct));
        my_ring[((m0 + s) & (RSLOT - 1)) * RSTR + lane] = x;
        if (MASKED) {
            const bool act = (unsigned)(m0 + s) < (unsigned)LLEN;
            prev_left = act ? cl : prev_left;
            prev_own  = act ? x  : prev_own;
        } else {
            prev_left = cl;
            prev_own  = x;
        }
    }
}

__global__ __launch_bounds__(256, 1)
void toeplitz_scan(const float* __restrict__ vin,   // inputs (L, 256)
                   const float* __restrict__ dtin,  // dt     (L, 256)
                   float* __restrict__ out)         // (L, 256, 256)
{
    extern __shared__ float lds[];
    float* g_arr = lds + G_OFF;   // [GPAD]
    float* b_arr = lds + B_OFF;   // [GPAD]
    float* ring  = lds + R_OFF;   // [4][RSLOT][RSTR], row-indexed slots

    const int ch  = blockIdx.x;
    const int tid = threadIdx.x;

    // ---- per-channel g[l], beta[l] (+ zero pad) ----
    #pragma unroll
    for (int k = 0; k < LLEN / 256; ++k) {
        const int l = tid + 256 * k;
        const float d = dtin[l * NCHAN + ch];
        const float u = vin[l * NCHAN + ch];
        const float ic = 1.0f / (1.0f + 0.25f * d);
        g_arr[l] = (1.0f - 0.25f * d) * ic;
        b_arr[l] = d * u * ic;
    }
    if (tid < GPAD - LLEN) {
        g_arr[LLEN + tid] = 1.0f;
        b_arr[LLEN + tid] = 0.0f;
    }
    __syncthreads();

    const int wave = tid >> 6, lane = tid & 63;
    const bool w0    = (wave == 0);
    const bool lane0 = (lane == 0);
    const int wskew  = wave * SKEW;

    float* my_ring = ring + wave * (RSLOT * RSTR);
    const float* lf_ring = ring + (wave > 0 ? (wave - 1) : 0) * (RSLOT * RSTR);

    float prev_own = 0.0f, prev_left = 0.0f;

    const int rq = lane >> 4;              // flush: row within 4-row group
    const int cq = (lane & 15) << 2;       // flush: col-quad start
    float* const out_col = out + (size_t)(ch * 256 + wave * 64 + cq);

    for (int c = 0; c < NCHUNK; ++c) {
        const int T0 = c * KCH;
        const int bl = T0 - wskew;         // lane0's row at s=0 (mult of 32)

        if (bl >= 0 && bl <= 1056) {       // any lane active this chunk
            const bool fast = (bl >= 64) && (bl <= LLEN - KCH);
            if (w0) {
                if (fast)
                    do_chunk<true, false>(T0, bl, lane, lane0, g_arr, b_arr,
                                          my_ring, prev_own, prev_left);
                else
                    do_chunk<true, true>(T0, bl, lane, lane0, g_arr, b_arr,
                                         my_ring, prev_own, prev_left);
            } else {
                if (fast)
                    do_chunk<false, false>(T0, bl, lane, lane0, g_arr, lf_ring,
                                           my_ring, prev_own, prev_left);
                else
                    do_chunk<false, true>(T0, bl, lane, lane0, g_arr, lf_ring,
                                          my_ring, prev_own, prev_left);
            }
        }

        // ---- flush rows [F, F+31] (4-row groups; complete at tick T0+30) --
        // Slot arithmetic: F&127 in {0,32,64,96}, +rq+4q <= +31 -> no wrap.
        const int F = T0 - wskew - 64;
        if (F >= 0 && F <= LLEN - KCH) {
            compiler_mem_fence();          // ring writes stay above reads
            const float* rb = my_ring + (F & (RSLOT - 1)) * RSTR + cq;
            float* ob = out_col + (size_t)(F + rq) * (NCHAN * 256);
            #pragma unroll
            for (int q = 0; q < 8; ++q) {
                const f32x4 v =
                    *reinterpret_cast<const f32x4*>(rb + (4 * q + rq) * RSTR);
                __builtin_nontemporal_store(v, reinterpret_cast<f32x4*>(ob));
                ob += (size_t)4 * (NCHAN * 256);
            }
        }
        lds_barrier();
    }
}

} // namespace

extern "C" void kernel_launch(void* const* d_in, const int* in_sizes, int n_in,
                              void* d_out, int out_size, void* d_ws, size_t ws_size,
                              hipStream_t stream) {
    (void)in_sizes; (void)n_in; (void)d_ws; (void)ws_size; (void)out_size;
    const float* vin  = (const float*)d_in[0];   // "inputs"
    const float* dtin = (const float*)d_in[1];   // "dt"
    float* out = (float*)d_out;

    (void)hipFuncSetAttribute(reinterpret_cast<const void*>(toeplitz_scan),
                              hipFuncAttributeMaxDynamicSharedMemorySize,
                              (int)LDS_BYTES);

    toeplitz_scan<<<NCHAN, 256, LDS_BYTES, stream>>>(vin, dtin, out);
}